// Round 7
// baseline (1209.397 us; speedup 1.0000x reference)
//
#include <hip/hip_runtime.h>
#include <hip/hip_fp16.h>

#define N_NODES 100000
#define N_EDGES 1600000
#define K_ITER 10

#define NSLICE 4
#define SLICE_SHIFT 15            // slice = col >> 15  (32768 nodes = 3.1 MB fp16 < 4 MiB L2)
#define M_SEG (N_NODES * NSLICE)  // 400000 CSR segments

#define TPN 8    // threads per node; each lane owns 6 feats (12 B fp16)
#define NPB 32   // nodes processed simultaneously per 256-thread block
#define NGRP 4   // node-groups per block -> 128 nodes/block
#define PBLOCKS ((N_NODES + NPB * NGRP - 1) / (NPB * NGRP))   // 782, ~3/CU co-resident

#define SCAN_TB   256
#define SCAN_EPT  8
#define SCAN_SEG  (SCAN_TB * SCAN_EPT)                        // 2048
#define SCAN_NB   ((M_SEG + SCAN_SEG - 1) / SCAN_SEG)         // 196

typedef unsigned int u32;
typedef u32   u32x3 __attribute__((ext_vector_type(3)));
typedef float f32x2 __attribute__((ext_vector_type(2)));

// ---------------------------------------------------------------------------
// pos_local[e] = cnt4[row*4 + slice(col)]++   (rank within (row,slice) segment)
__global__ void k_count(const int* __restrict__ row, const int* __restrict__ col,
                        int* __restrict__ cnt4, unsigned char* __restrict__ pos_local,
                        int E) {
    int i = blockIdx.x * blockDim.x + threadIdx.x;
    if (i < E) {
        int idx = row[i] * NSLICE + (col[i] >> SLICE_SHIFT);
        pos_local[i] = (unsigned char)atomicAdd(&cnt4[idx], 1);
    }
}

__global__ void k_scanA(const int* __restrict__ cnt4, int* __restrict__ thread_off,
                        int* __restrict__ blocksum) {
    __shared__ int sh[SCAN_TB];
    int b = blockIdx.x, t = threadIdx.x;
    int base = b * SCAN_SEG + t * SCAN_EPT;
    int s = 0;
#pragma unroll
    for (int j = 0; j < SCAN_EPT; ++j) {
        int i = base + j;
        if (i < M_SEG) s += cnt4[i];
    }
    sh[t] = s;
    __syncthreads();
    for (int off = 1; off < SCAN_TB; off <<= 1) {
        int v = (t >= off) ? sh[t - off] : 0;
        __syncthreads();
        sh[t] += v;
        __syncthreads();
    }
    thread_off[b * SCAN_TB + t] = sh[t] - s;
    if (t == SCAN_TB - 1) blocksum[b] = sh[t];
}

// Parallel scan of the 196 block sums (one 256-thread block, LDS Hillis-Steele)
__global__ void k_scanB(const int* __restrict__ blocksum, int* __restrict__ blockoff,
                        int* __restrict__ rowptr4) {
    __shared__ int sh[SCAN_TB];
    int t = threadIdx.x;
    int v = (t < SCAN_NB) ? blocksum[t] : 0;
    sh[t] = v;
    __syncthreads();
    for (int off = 1; off < SCAN_TB; off <<= 1) {
        int u = (t >= off) ? sh[t - off] : 0;
        __syncthreads();
        sh[t] += u;
        __syncthreads();
    }
    if (t < SCAN_NB) blockoff[t] = sh[t] - v;
    if (t == SCAN_NB - 1) rowptr4[M_SEG] = sh[t];
}

__global__ void k_scanC(const int* __restrict__ cnt4, const int* __restrict__ thread_off,
                        const int* __restrict__ blockoff, int* __restrict__ rowptr4) {
    int b = blockIdx.x, t = threadIdx.x;
    int base = b * SCAN_SEG + t * SCAN_EPT;
    int run = blockoff[b] + thread_off[b * SCAN_TB + t];
#pragma unroll
    for (int j = 0; j < SCAN_EPT; ++j) {
        int i = base + j;
        if (i < M_SEG) {
            rowptr4[i] = run;
            run += cnt4[i];
        }
    }
}

// Atomic-free fill. epack4 = (col << 15) | (fp32bits(w) >> 17)  [sign+exp+6 mant]
__global__ void k_fill(const int* __restrict__ row, const int* __restrict__ col,
                       const float* __restrict__ w, const int* __restrict__ rowptr4,
                       const unsigned char* __restrict__ pos_local,
                       u32* __restrict__ epack4, int E) {
    int i = blockIdx.x * blockDim.x + threadIdx.x;
    if (i < E) {
        int r = row[i], c = col[i];
        int pos = rowptr4[r * NSLICE + (c >> SLICE_SHIFT)] + (int)pos_local[i];
        epack4[pos] = ((u32)c << 15) | (__float_as_uint(w[i]) >> 17);
    }
}

// scale[n] = 0.9 / (sum of quantized w over the whole row + 1e-10)
__global__ void k_scale(const int* __restrict__ rowptr4, const u32* __restrict__ epack4,
                        float* __restrict__ scale) {
    int n = blockIdx.x * blockDim.x + threadIdx.x;
    if (n >= N_NODES) return;
    int beg = rowptr4[n * NSLICE], end = rowptr4[n * NSLICE + NSLICE];
    float s = 0.f;
    for (int e = beg; e < end; ++e)
        s += __uint_as_float((epack4[e] & 0x7fffu) << 17);
    scale[n] = 0.9f / (s + 1e-10f);
}

// x (fp32) -> fp16 h0 buffer. Thread i converts 8 floats.
__global__ void k_x2h(const float4* __restrict__ x, float4* __restrict__ x16, int n8) {
    int i = blockIdx.x * blockDim.x + threadIdx.x;
    if (i < n8) {
        float4 a = x[2 * i], b = x[2 * i + 1];
        float4 o;
        ((__half2*)&o)[0] = __floats2half2_rn(a.x, a.y);
        ((__half2*)&o)[1] = __floats2half2_rn(a.z, a.w);
        ((__half2*)&o)[2] = __floats2half2_rn(b.x, b.y);
        ((__half2*)&o)[3] = __floats2half2_rn(b.z, b.w);
        x16[i] = o;
    }
}

// ---------------------------------------------------------------------------
// Persistent phased pull. Block owns 128 contiguous nodes; accumulators live in
// registers across the 4 source-slice phases so all co-resident blocks gather
// from the same 3.1 MB slice at the same time (L2-resident gathers).
template <int LAST>
__global__ __launch_bounds__(256) void k_pull(const int* __restrict__ rowptr4,
                                              const u32* __restrict__ epack4,
                                              const float* __restrict__ scale,
                                              const float* __restrict__ x,
                                              const __half* __restrict__ src16,
                                              void* __restrict__ dstv) {
    int lane = threadIdx.x & (TPN - 1);   // feature chunk (6 floats)
    int sub  = threadIdx.x >> 3;          // node within group (0..31)
    int base = blockIdx.x * (NPB * NGRP);

    float acc[NGRP][6];
    float scN[NGRP];
    int   nodes[NGRP];

    // init: acc = 0.1 * x[n]  (nontemporal: don't pollute L2)
#pragma unroll
    for (int g = 0; g < NGRP; ++g) {
        int n = base + g * NPB + sub;
        nodes[g] = n;
        if (n < N_NODES) {
            const f32x2* xp = (const f32x2*)(x + n * 48 + lane * 6);
            f32x2 v0 = __builtin_nontemporal_load(xp);
            f32x2 v1 = __builtin_nontemporal_load(xp + 1);
            f32x2 v2 = __builtin_nontemporal_load(xp + 2);
            acc[g][0] = 0.1f * v0.x; acc[g][1] = 0.1f * v0.y;
            acc[g][2] = 0.1f * v1.x; acc[g][3] = 0.1f * v1.y;
            acc[g][4] = 0.1f * v2.x; acc[g][5] = 0.1f * v2.y;
            scN[g] = scale[n];
        } else {
            scN[g] = 0.f;
#pragma unroll
            for (int j = 0; j < 6; ++j) acc[g][j] = 0.f;
        }
    }

    // phases: one source slice at a time
    for (int p = 0; p < NSLICE; ++p) {
#pragma unroll
        for (int g = 0; g < NGRP; ++g) {
            int n = nodes[g];
            if (n >= N_NODES) continue;
            int beg = rowptr4[n * NSLICE + p];
            int end = rowptr4[n * NSLICE + p + 1];
            for (int e = beg; e < end; ++e) {
                u32 u = __builtin_nontemporal_load(epack4 + e);
                float wv = __uint_as_float((u & 0x7fffu) << 17) * scN[g];
                int cidx = (int)(u >> 15);
                const u32x3* hp = (const u32x3*)(src16 + cidx * 48 + lane * 6);
                u32x3 hv = *hp;                      // 12 B gather (L2-resident slice)
                u32 w0 = hv.x, w1 = hv.y, w2 = hv.z;
                float2 f0 = __half22float2(*(__half2*)&w0);
                float2 f1 = __half22float2(*(__half2*)&w1);
                float2 f2 = __half22float2(*(__half2*)&w2);
                acc[g][0] += wv * f0.x; acc[g][1] += wv * f0.y;
                acc[g][2] += wv * f1.x; acc[g][3] += wv * f1.y;
                acc[g][4] += wv * f2.x; acc[g][5] += wv * f2.y;
            }
        }
    }

    // epilogue
#pragma unroll
    for (int g = 0; g < NGRP; ++g) {
        int n = nodes[g];
        if (n >= N_NODES) continue;
        if (LAST) {
            f32x2* op = (f32x2*)((float*)dstv + n * 48 + lane * 6);
            f32x2 o0; o0.x = acc[g][0]; o0.y = acc[g][1];
            f32x2 o1; o1.x = acc[g][2]; o1.y = acc[g][3];
            f32x2 o2; o2.x = acc[g][4]; o2.y = acc[g][5];
            __builtin_nontemporal_store(o0, op);
            __builtin_nontemporal_store(o1, op + 1);
            __builtin_nontemporal_store(o2, op + 2);
        } else {
            __half2 h0 = __floats2half2_rn(acc[g][0], acc[g][1]);
            __half2 h1 = __floats2half2_rn(acc[g][2], acc[g][3]);
            __half2 h2 = __floats2half2_rn(acc[g][4], acc[g][5]);
            u32x3 o;
            o.x = *(u32*)&h0; o.y = *(u32*)&h1; o.z = *(u32*)&h2;
            u32x3* dp = (u32x3*)((__half*)dstv + n * 48 + lane * 6);
            __builtin_nontemporal_store(o, dp);
        }
    }
}

extern "C" void kernel_launch(void* const* d_in, const int* in_sizes, int n_in,
                              void* d_out, int out_size, void* d_ws, size_t ws_size,
                              hipStream_t stream) {
    const float* x  = (const float*)d_in[0];
    const int*   ei = (const int*)d_in[1];
    const float* w  = (const float*)d_in[2];
    const int E = in_sizes[2];
    const int* row = ei;        // destination (segment id)
    const int* col = ei + E;    // message source

    // Workspace layout (16B-aligned), total 31.0 MB:
    //   rowptr4    @ 0           int[M+1]     -> 1,600,016
    //   epack4     @ 1,600,016   u32[E]       -> 8,000,016
    //   scale      @ 8,000,016   float[N]     -> 8,400,016
    //   thread_off @ 8,400,016   int[196*256] -> 8,600,736 (pad)
    //   blocksum   @ 8,600,736   int[196]     -> 8,601,536 (pad)
    //   blockoff   @ 8,601,536   int[196]     -> 8,602,336 (pad)
    //   cnt4       @ 8,602,336   int[M]       -> 10,202,336
    //   pos_local  @ 10,202,336  u8[E]        -> 11,802,336
    //   hA16       @ 11,802,336  half[N*48]   -> 21,402,336
    //   hB16       @ 21,402,336  half[N*48]   -> 31,002,336
    char* ws = (char*)d_ws;
    int*           rowptr4    = (int*)(ws);
    u32*           epack4     = (u32*)(ws + 1600016);
    float*         scale      = (float*)(ws + 8000016);
    int*           thread_off = (int*)(ws + 8400016);
    int*           blocksum   = (int*)(ws + 8600736);
    int*           blockoff   = (int*)(ws + 8601536);
    int*           cnt4       = (int*)(ws + 8602336);
    unsigned char* pos_local  = (unsigned char*)(ws + 10202336);
    __half*        hA16       = (__half*)(ws + 11802336);
    __half*        hB16       = (__half*)(ws + 21402336);

    const int B = 256;
    const int egrid = (E + B - 1) / B;
    const int ngrid = (N_NODES + B - 1) / B;

    hipMemsetAsync(cnt4, 0, M_SEG * sizeof(int), stream);
    k_count<<<egrid, B, 0, stream>>>(row, col, cnt4, pos_local, E);
    k_scanA<<<SCAN_NB, SCAN_TB, 0, stream>>>(cnt4, thread_off, blocksum);
    k_scanB<<<1, SCAN_TB, 0, stream>>>(blocksum, blockoff, rowptr4);
    k_scanC<<<SCAN_NB, SCAN_TB, 0, stream>>>(cnt4, thread_off, blockoff, rowptr4);
    k_fill <<<egrid, B, 0, stream>>>(row, col, w, rowptr4, pos_local, epack4, E);
    k_scale<<<ngrid, B, 0, stream>>>(rowptr4, epack4, scale);

    const int n8 = N_NODES * 6;   // 8-float chunks of x
    k_x2h<<<(n8 + B - 1) / B, B, 0, stream>>>((const float4*)x, (float4*)hA16, n8);

    // iters 1..9 fp16 ping-pong (1: A->B, 2: B->A, ... 9: A->B); iter 10: B->out
    __half* src = hA16;
    __half* dst = hB16;
    for (int k = 1; k <= K_ITER - 1; ++k) {
        k_pull<0><<<PBLOCKS, 256, 0, stream>>>(rowptr4, epack4, scale, x, src, dst);
        __half* t = src; src = dst; dst = t;
    }
    k_pull<1><<<PBLOCKS, 256, 0, stream>>>(rowptr4, epack4, scale, x, src, d_out);
}

// Round 8
// 546.424 us; speedup vs baseline: 2.2133x; 2.2133x over previous
//
#include <hip/hip_runtime.h>
#include <hip/hip_fp16.h>

#define N_NODES 100000
#define N_EDGES 1600000
#define K_ITER 10

#define TPN 12   // threads per node; lane owns 4 feats (8 B fp16 gather)
#define NPB 16   // nodes per block (192 threads = 3 waves)
#define PAD 8    // row length padded to multiple of 8 (zero-edges)

#define SCAN_TB   256
#define SCAN_EPT  8
#define SCAN_SEG  (SCAN_TB * SCAN_EPT)
#define SCAN_NB   ((N_NODES + SCAN_SEG - 1) / SCAN_SEG)   // 49

typedef unsigned int u32;

// ---------------------------------------------------------------------------
// Packed u16 degree counters: cnt2[r>>1] halves hold rows 2i / 2i+1.
// pos_local[e] = rank of edge within its row.
__global__ void k_count(const int* __restrict__ row, u32* __restrict__ cnt2,
                        unsigned char* __restrict__ pos_local, int E) {
    int i = blockIdx.x * blockDim.x + threadIdx.x;
    if (i < E) {
        int r = row[i];
        u32 inc = (r & 1) ? 0x10000u : 1u;
        u32 old = atomicAdd(&cnt2[r >> 1], inc);
        pos_local[i] = (unsigned char)((old >> ((r & 1) * 16)) & 0xffffu);
    }
}

__device__ __forceinline__ int padded_cnt(const u32* cnt2, int i) {
    int cv = (int)((cnt2[i >> 1] >> ((i & 1) * 16)) & 0xffffu);
    return (cv + (PAD - 1)) & ~(PAD - 1);
}

__global__ void k_scanA(const u32* __restrict__ cnt2, int* __restrict__ thread_off,
                        int* __restrict__ blocksum) {
    __shared__ int sh[SCAN_TB];
    int b = blockIdx.x, t = threadIdx.x;
    int base = b * SCAN_SEG + t * SCAN_EPT;
    int s = 0;
#pragma unroll
    for (int j = 0; j < SCAN_EPT; ++j) {
        int i = base + j;
        if (i < N_NODES) s += padded_cnt(cnt2, i);
    }
    sh[t] = s;
    __syncthreads();
    for (int off = 1; off < SCAN_TB; off <<= 1) {
        int v = (t >= off) ? sh[t - off] : 0;
        __syncthreads();
        sh[t] += v;
        __syncthreads();
    }
    thread_off[b * SCAN_TB + t] = sh[t] - s;
    if (t == SCAN_TB - 1) blocksum[b] = sh[t];
}

// Parallel scan of 49 block sums (one 256-thread block)
__global__ void k_scanB(const int* __restrict__ blocksum, int* __restrict__ blockoff,
                        int* __restrict__ rowptr) {
    __shared__ int sh[SCAN_TB];
    int t = threadIdx.x;
    int v = (t < SCAN_NB) ? blocksum[t] : 0;
    sh[t] = v;
    __syncthreads();
    for (int off = 1; off < SCAN_TB; off <<= 1) {
        int u = (t >= off) ? sh[t - off] : 0;
        __syncthreads();
        sh[t] += u;
        __syncthreads();
    }
    if (t < SCAN_NB) blockoff[t] = sh[t] - v;
    if (t == SCAN_NB - 1) rowptr[N_NODES] = sh[t];
}

__global__ void k_scanC(const u32* __restrict__ cnt2, const int* __restrict__ thread_off,
                        const int* __restrict__ blockoff, int* __restrict__ rowptr) {
    int b = blockIdx.x, t = threadIdx.x;
    int base = b * SCAN_SEG + t * SCAN_EPT;
    int run = blockoff[b] + thread_off[b * SCAN_TB + t];
#pragma unroll
    for (int j = 0; j < SCAN_EPT; ++j) {
        int i = base + j;
        if (i < N_NODES) {
            rowptr[i] = run;
            run += padded_cnt(cnt2, i);
        }
    }
}

// Atomic-free fill: epack[rowptr[r]+pos] = (col<<15) | (fp32bits(w)>>17).
// Pad slots stay 0 from the memset (col=0, w=+0.0 -> harmless hot-line gather).
__global__ void k_fill(const int* __restrict__ row, const int* __restrict__ col,
                       const float* __restrict__ w, const int* __restrict__ rowptr,
                       const unsigned char* __restrict__ pos_local,
                       u32* __restrict__ epack, int E) {
    int i = blockIdx.x * blockDim.x + threadIdx.x;
    if (i < E) {
        int pos = rowptr[row[i]] + (int)pos_local[i];
        epack[pos] = ((u32)col[i] << 15) | (__float_as_uint(w[i]) >> 17);
    }
}

// scale[n] = 0.9 / (sum of quantized w + 1e-10); zeros in pad slots add 0.
__global__ void k_scale(const int* __restrict__ rowptr, const u32* __restrict__ epack,
                        float* __restrict__ scale) {
    int n = blockIdx.x * blockDim.x + threadIdx.x;
    if (n >= N_NODES) return;
    int beg = rowptr[n], end = rowptr[n + 1];
    float s = 0.f;
    for (int e = beg; e < end; ++e)
        s += __uint_as_float((epack[e] & 0x7fffu) << 17);
    scale[n] = 0.9f / (s + 1e-10f);
}

// x (fp32) -> fp16. Thread i converts 8 floats.
__global__ void k_x2h(const float4* __restrict__ x, float4* __restrict__ x16, int n8) {
    int i = blockIdx.x * blockDim.x + threadIdx.x;
    if (i < n8) {
        float4 a = x[2 * i], b = x[2 * i + 1];
        float4 o;
        ((__half2*)&o)[0] = __floats2half2_rn(a.x, a.y);
        ((__half2*)&o)[1] = __floats2half2_rn(a.z, a.w);
        ((__half2*)&o)[2] = __floats2half2_rn(b.x, b.y);
        ((__half2*)&o)[3] = __floats2half2_rn(b.z, b.w);
        x16[i] = o;
    }
}

// ---------------------------------------------------------------------------
// Pull: dst[n] = 0.1*x[n] + sum_e w*scale*h[col]. Rows are multiples of 8 ->
// branchless unroll-8 (8 outstanding 8B gathers per lane). 12 lanes per node.
#define GATHER_FMA(UJ, ACC)                                                    \
    {                                                                          \
        u32 uu = (UJ);                                                         \
        float2 hv = src16[(uu >> 15) * TPN + c];                               \
        float wv = __uint_as_float((uu & 0x7fffu) << 17) * sc;                 \
        float2 fa = __half22float2(*(__half2*)&hv.x);                          \
        float2 fb = __half22float2(*(__half2*)&hv.y);                          \
        ACC.x += wv * fa.x; ACC.y += wv * fa.y;                                \
        ACC.z += wv * fb.x; ACC.w += wv * fb.y;                                \
    }

template <int LAST>
__global__ __launch_bounds__(192) void k_pull(const int* __restrict__ rowptr,
                                              const u32* __restrict__ epack,
                                              const float* __restrict__ scale,
                                              const float4* __restrict__ x,
                                              const float2* __restrict__ src16,
                                              void* __restrict__ dstv) {
    int node = blockIdx.x * NPB + threadIdx.x / TPN;
    int c = threadIdx.x % TPN;
    if (node >= N_NODES) return;
    int beg = rowptr[node], end = rowptr[node + 1];
    float sc = scale[node];
    float4 xv = x[node * TPN + c];
    float4 a0 = make_float4(0.1f * xv.x, 0.1f * xv.y, 0.1f * xv.z, 0.1f * xv.w);
    float4 a1 = make_float4(0, 0, 0, 0);
    float4 a2 = make_float4(0, 0, 0, 0);
    float4 a3 = make_float4(0, 0, 0, 0);
    for (int e = beg; e < end; e += 8) {
        const uint4* ep = (const uint4*)(epack + e);   // 32B-aligned (PAD=8)
        uint4 pa = ep[0], pb = ep[1];
        GATHER_FMA(pa.x, a0) GATHER_FMA(pa.y, a1)
        GATHER_FMA(pa.z, a2) GATHER_FMA(pa.w, a3)
        GATHER_FMA(pb.x, a0) GATHER_FMA(pb.y, a1)
        GATHER_FMA(pb.z, a2) GATHER_FMA(pb.w, a3)
    }
    float4 acc = make_float4(a0.x + a1.x + a2.x + a3.x, a0.y + a1.y + a2.y + a3.y,
                             a0.z + a1.z + a2.z + a3.z, a0.w + a1.w + a2.w + a3.w);
    if (LAST) {
        ((float4*)dstv)[node * TPN + c] = acc;
    } else {
        float2 o;
        *(__half2*)&o.x = __floats2half2_rn(acc.x, acc.y);
        *(__half2*)&o.y = __floats2half2_rn(acc.z, acc.w);
        ((float2*)dstv)[node * TPN + c] = o;
    }
}

extern "C" void kernel_launch(void* const* d_in, const int* in_sizes, int n_in,
                              void* d_out, int out_size, void* d_ws, size_t ws_size,
                              hipStream_t stream) {
    const float* x  = (const float*)d_in[0];
    const int*   ei = (const int*)d_in[1];
    const float* w  = (const float*)d_in[2];
    const int E = in_sizes[2];
    const int* row = ei;        // destination (segment id)
    const int* col = ei + E;    // message source

    // Workspace (16B-aligned), total ~31.1 MB:
    //   rowptr     @ 0           int[N+1]          -> 400,016
    //   epack      @ 400,016     u32[E+7N+16]      -> 9,600,096  (9,200,064 B)
    //   scale      @ 9,600,096   float[N]          -> 10,000,096
    //   thread_off @ 10,000,096  int[49*256]       -> 10,050,272
    //   blocksum   @ 10,050,272  int[256]          -> 10,051,296
    //   blockoff   @ 10,051,296  int[256]          -> 10,052,320
    //   cnt2       @ 10,052,320  u32[N/2]          -> 10,252,320
    //   pos_local  @ 10,252,320  u8[E]             -> 11,852,320
    //   hA16       @ 11,852,320  half[N*48]        -> 21,452,320
    //   hB16       @ 21,452,320  half[N*48]        -> 31,052,320
    char* ws = (char*)d_ws;
    int*           rowptr     = (int*)(ws);
    u32*           epack      = (u32*)(ws + 400016);
    float*         scale      = (float*)(ws + 9600096);
    int*           thread_off = (int*)(ws + 10000096);
    int*           blocksum   = (int*)(ws + 10050272);
    int*           blockoff   = (int*)(ws + 10051296);
    u32*           cnt2       = (u32*)(ws + 10052320);
    unsigned char* pos_local  = (unsigned char*)(ws + 10252320);
    __half*        hA16       = (__half*)(ws + 11852320);
    __half*        hB16       = (__half*)(ws + 21452320);

    const int B = 256;
    const int egrid = (E + B - 1) / B;
    const int ngrid = (N_NODES + B - 1) / B;
    const int pgrid = (N_NODES + NPB - 1) / NPB;

    hipMemsetAsync(cnt2, 0, (N_NODES / 2) * sizeof(u32), stream);
    hipMemsetAsync(epack, 0, (size_t)(E + 7 * N_NODES + 16) * sizeof(u32), stream);
    k_count<<<egrid, B, 0, stream>>>(row, cnt2, pos_local, E);
    k_scanA<<<SCAN_NB, SCAN_TB, 0, stream>>>(cnt2, thread_off, blocksum);
    k_scanB<<<1, SCAN_TB, 0, stream>>>(blocksum, blockoff, rowptr);
    k_scanC<<<SCAN_NB, SCAN_TB, 0, stream>>>(cnt2, thread_off, blockoff, rowptr);
    k_fill <<<egrid, B, 0, stream>>>(row, col, w, rowptr, pos_local, epack, E);
    k_scale<<<ngrid, B, 0, stream>>>(rowptr, epack, scale);

    const int n8 = N_NODES * 6;   // 8-float chunks of x
    k_x2h<<<(n8 + B - 1) / B, B, 0, stream>>>((const float4*)x, (float4*)hA16, n8);

    // iters 1..9 fp16 ping-pong; iter 10 writes fp32 d_out
    __half* src = hA16;
    __half* dst = hB16;
    for (int k = 1; k <= K_ITER - 1; ++k) {
        k_pull<0><<<pgrid, NPB * TPN, 0, stream>>>(rowptr, epack, scale,
                                                   (const float4*)x,
                                                   (const float2*)src, dst);
        __half* t = src; src = dst; dst = t;
    }
    k_pull<1><<<pgrid, NPB * TPN, 0, stream>>>(rowptr, epack, scale,
                                               (const float4*)x,
                                               (const float2*)src, d_out);
}

// Round 9
// 499.744 us; speedup vs baseline: 2.4200x; 1.0934x over previous
//
#include <hip/hip_runtime.h>
#include <hip/hip_fp16.h>

#define N_NODES 100000
#define N_EDGES 1600000
#define K_ITER 10

#define TPN 6    // threads per node; lane owns 8 feats (16 B fp16 gather)
#define NPB 32   // nodes per block (192 threads = 3 waves)
#define PAD 4    // row length padded to multiple of 4 (zero-edges)
#define RS 8     // h-row stride in float4 units: 128 B (one L2 line), 96 B used

#define SCAN_TB   256
#define SCAN_EPT  8
#define SCAN_SEG  (SCAN_TB * SCAN_EPT)
#define SCAN_NB   ((N_NODES + SCAN_SEG - 1) / SCAN_SEG)   // 49

typedef unsigned int u32;

// ---------------------------------------------------------------------------
// Packed u16 degree counters; pos_local[e] = rank of edge within its row.
__global__ void k_count(const int* __restrict__ row, u32* __restrict__ cnt2,
                        unsigned char* __restrict__ pos_local, int E) {
    int i = blockIdx.x * blockDim.x + threadIdx.x;
    if (i < E) {
        int r = row[i];
        u32 inc = (r & 1) ? 0x10000u : 1u;
        u32 old = atomicAdd(&cnt2[r >> 1], inc);
        pos_local[i] = (unsigned char)((old >> ((r & 1) * 16)) & 0xffffu);
    }
}

__device__ __forceinline__ int padded_cnt(const u32* cnt2, int i) {
    int cv = (int)((cnt2[i >> 1] >> ((i & 1) * 16)) & 0xffffu);
    return (cv + (PAD - 1)) & ~(PAD - 1);
}

__global__ void k_scanA(const u32* __restrict__ cnt2, int* __restrict__ thread_off,
                        int* __restrict__ blocksum) {
    __shared__ int sh[SCAN_TB];
    int b = blockIdx.x, t = threadIdx.x;
    int base = b * SCAN_SEG + t * SCAN_EPT;
    int s = 0;
#pragma unroll
    for (int j = 0; j < SCAN_EPT; ++j) {
        int i = base + j;
        if (i < N_NODES) s += padded_cnt(cnt2, i);
    }
    sh[t] = s;
    __syncthreads();
    for (int off = 1; off < SCAN_TB; off <<= 1) {
        int v = (t >= off) ? sh[t - off] : 0;
        __syncthreads();
        sh[t] += v;
        __syncthreads();
    }
    thread_off[b * SCAN_TB + t] = sh[t] - s;
    if (t == SCAN_TB - 1) blocksum[b] = sh[t];
}

__global__ void k_scanB(const int* __restrict__ blocksum, int* __restrict__ blockoff,
                        int* __restrict__ rowptr) {
    __shared__ int sh[SCAN_TB];
    int t = threadIdx.x;
    int v = (t < SCAN_NB) ? blocksum[t] : 0;
    sh[t] = v;
    __syncthreads();
    for (int off = 1; off < SCAN_TB; off <<= 1) {
        int u = (t >= off) ? sh[t - off] : 0;
        __syncthreads();
        sh[t] += u;
        __syncthreads();
    }
    if (t < SCAN_NB) blockoff[t] = sh[t] - v;
    if (t == SCAN_NB - 1) rowptr[N_NODES] = sh[t];
}

__global__ void k_scanC(const u32* __restrict__ cnt2, const int* __restrict__ thread_off,
                        const int* __restrict__ blockoff, int* __restrict__ rowptr) {
    int b = blockIdx.x, t = threadIdx.x;
    int base = b * SCAN_SEG + t * SCAN_EPT;
    int run = blockoff[b] + thread_off[b * SCAN_TB + t];
#pragma unroll
    for (int j = 0; j < SCAN_EPT; ++j) {
        int i = base + j;
        if (i < N_NODES) {
            rowptr[i] = run;
            run += padded_cnt(cnt2, i);
        }
    }
}

// Atomic-free fill: epack[rowptr[r]+pos] = (col<<15) | (fp32bits(w)>>17).
// Pad slots stay 0 from the memset (col=0, w=+0.0 -> harmless hot-line gather).
__global__ void k_fill(const int* __restrict__ row, const int* __restrict__ col,
                       const float* __restrict__ w, const int* __restrict__ rowptr,
                       const unsigned char* __restrict__ pos_local,
                       u32* __restrict__ epack, int E) {
    int i = blockIdx.x * blockDim.x + threadIdx.x;
    if (i < E) {
        int pos = rowptr[row[i]] + (int)pos_local[i];
        epack[pos] = ((u32)col[i] << 15) | (__float_as_uint(w[i]) >> 17);
    }
}

// scale[n] = 0.9 / (sum of quantized w + 1e-10); zeros in pad slots add 0.
__global__ void k_scale(const int* __restrict__ rowptr, const u32* __restrict__ epack,
                        float* __restrict__ scale) {
    int n = blockIdx.x * blockDim.x + threadIdx.x;
    if (n >= N_NODES) return;
    int beg = rowptr[n], end = rowptr[n + 1];
    float s = 0.f;
    for (int e = beg; e < end; ++e)
        s += __uint_as_float((epack[e] & 0x7fffu) << 17);
    scale[n] = 0.9f / (s + 1e-10f);
}

// x (fp32, dense 48) -> fp16 rows padded to 128 B stride.
// 6 threads per node, each converts 8 floats -> one float4 of halves.
__global__ void k_x2h(const float4* __restrict__ x, float4* __restrict__ x16) {
    int i = blockIdx.x * blockDim.x + threadIdx.x;   // < N*6
    int n = i / TPN, c = i % TPN;
    if (n >= N_NODES) return;
    float4 a = x[n * 12 + 2 * c], b = x[n * 12 + 2 * c + 1];
    float4 o;
    ((__half2*)&o)[0] = __floats2half2_rn(a.x, a.y);
    ((__half2*)&o)[1] = __floats2half2_rn(a.z, a.w);
    ((__half2*)&o)[2] = __floats2half2_rn(b.x, b.y);
    ((__half2*)&o)[3] = __floats2half2_rn(b.z, b.w);
    x16[(n << 3) + c] = o;   // row stride RS=8 float4s
}

// ---------------------------------------------------------------------------
// Pull: dst[n] = 0.1*x[n] + sum_e w*scale*h[col]. Rows multiple of 4 ->
// branchless unroll-4, 16 B gathers, each within ONE 128 B line.
#define GFMA(UJ, AA, BB)                                                      \
    {                                                                         \
        u32 uu = (UJ);                                                        \
        float4 hv = src16[((uu >> 15) << 3) + c];                             \
        float wv = __uint_as_float((uu & 0x7fffu) << 17) * sc;                \
        float2 f0 = __half22float2(*(__half2*)&hv.x);                         \
        float2 f1 = __half22float2(*(__half2*)&hv.y);                         \
        float2 f2 = __half22float2(*(__half2*)&hv.z);                         \
        float2 f3 = __half22float2(*(__half2*)&hv.w);                         \
        AA.x += wv * f0.x; AA.y += wv * f0.y; AA.z += wv * f1.x; AA.w += wv * f1.y; \
        BB.x += wv * f2.x; BB.y += wv * f2.y; BB.z += wv * f3.x; BB.w += wv * f3.y; \
    }

template <int LAST>
__global__ __launch_bounds__(192) void k_pull(const int* __restrict__ rowptr,
                                              const u32* __restrict__ epack,
                                              const float* __restrict__ scale,
                                              const float4* __restrict__ x,
                                              const float4* __restrict__ src16,
                                              void* __restrict__ dstv) {
    int node = blockIdx.x * NPB + threadIdx.x / TPN;
    int c = threadIdx.x % TPN;
    if (node >= N_NODES) return;
    int beg = rowptr[node], end = rowptr[node + 1];
    float sc = scale[node];
    float4 xa = x[node * 12 + 2 * c], xb = x[node * 12 + 2 * c + 1];
    float4 A0 = make_float4(0.1f * xa.x, 0.1f * xa.y, 0.1f * xa.z, 0.1f * xa.w);
    float4 B0 = make_float4(0.1f * xb.x, 0.1f * xb.y, 0.1f * xb.z, 0.1f * xb.w);
    float4 A1 = make_float4(0, 0, 0, 0), B1 = make_float4(0, 0, 0, 0);
    for (int e = beg; e < end; e += 4) {
        uint4 p = *(const uint4*)(epack + e);   // 16B-aligned (PAD=4)
        GFMA(p.x, A0, B0) GFMA(p.y, A1, B1)
        GFMA(p.z, A0, B0) GFMA(p.w, A1, B1)
    }
    float4 RA = make_float4(A0.x + A1.x, A0.y + A1.y, A0.z + A1.z, A0.w + A1.w);
    float4 RB = make_float4(B0.x + B1.x, B0.y + B1.y, B0.z + B1.z, B0.w + B1.w);
    if (LAST) {
        float4* out = (float4*)dstv;
        out[node * 12 + 2 * c]     = RA;
        out[node * 12 + 2 * c + 1] = RB;
    } else {
        float4 o;
        ((__half2*)&o)[0] = __floats2half2_rn(RA.x, RA.y);
        ((__half2*)&o)[1] = __floats2half2_rn(RA.z, RA.w);
        ((__half2*)&o)[2] = __floats2half2_rn(RB.x, RB.y);
        ((__half2*)&o)[3] = __floats2half2_rn(RB.z, RB.w);
        ((float4*)dstv)[(node << 3) + c] = o;
    }
}

extern "C" void kernel_launch(void* const* d_in, const int* in_sizes, int n_in,
                              void* d_out, int out_size, void* d_ws, size_t ws_size,
                              hipStream_t stream) {
    const float* x  = (const float*)d_in[0];
    const int*   ei = (const int*)d_in[1];
    const float* w  = (const float*)d_in[2];
    const int E = in_sizes[2];
    const int* row = ei;        // destination (segment id)
    const int* col = ei + E;    // message source

    // Workspace (16B-aligned), total ~23.1 MB. The SECOND fp16 ping-pong
    // buffer lives in d_out (12.8 MB of its 19.2 MB): with 9 fp16 pulls the
    // odd buffer (A, in d_out) is dead before the final fp32 write to d_out.
    //   rowptr     @ 0           int[N+1]          -> 400,016
    //   epack      @ 400,016     u32[E+3N+16]      -> 8,000,096
    //   scale      @ 8,000,096   float[N]          -> 8,400,096
    //   thread_off @ 8,400,096   int[49*256]       -> 8,450,272
    //   blocksum   @ 8,450,272   int[256]          -> 8,451,296
    //   blockoff   @ 8,451,296   int[256]          -> 8,452,320
    //   cnt2       @ 8,452,320   u32[N/2]          -> 8,652,320
    //   pos_local  @ 8,652,320   u8[E]             -> 10,252,320
    //   hB16       @ 10,252,320  128B*N            -> 23,052,320
    char* ws = (char*)d_ws;
    int*           rowptr     = (int*)(ws);
    u32*           epack      = (u32*)(ws + 400016);
    float*         scale      = (float*)(ws + 8000096);
    int*           thread_off = (int*)(ws + 8400096);
    int*           blocksum   = (int*)(ws + 8450272);
    int*           blockoff   = (int*)(ws + 8451296);
    u32*           cnt2       = (u32*)(ws + 8452320);
    unsigned char* pos_local  = (unsigned char*)(ws + 8652320);
    float4*        hB16       = (float4*)(ws + 10252320);
    float4*        hA16       = (float4*)d_out;      // x16 + odd ping-pong buffer

    const int B = 256;
    const int egrid = (E + B - 1) / B;
    const int ngrid = (N_NODES + B - 1) / B;
    const int pgrid = N_NODES / NPB;                 // 3125, exact
    const int xgrid = (N_NODES * TPN + 191) / 192;

    hipMemsetAsync(cnt2, 0, (N_NODES / 2) * sizeof(u32), stream);
    hipMemsetAsync(epack, 0, (size_t)(E + 3 * N_NODES + 16) * sizeof(u32), stream);
    k_count<<<egrid, B, 0, stream>>>(row, cnt2, pos_local, E);
    k_scanA<<<SCAN_NB, SCAN_TB, 0, stream>>>(cnt2, thread_off, blocksum);
    k_scanB<<<1, SCAN_TB, 0, stream>>>(blocksum, blockoff, rowptr);
    k_scanC<<<SCAN_NB, SCAN_TB, 0, stream>>>(cnt2, thread_off, blockoff, rowptr);
    k_fill <<<egrid, B, 0, stream>>>(row, col, w, rowptr, pos_local, epack, E);
    k_scale<<<ngrid, B, 0, stream>>>(rowptr, epack, scale);
    k_x2h  <<<xgrid, 192, 0, stream>>>((const float4*)x, hA16);

    // p1: A->B, p2: B->A, ..., p9: A->B (9 fp16 pulls); p10: B -> d_out fp32
    float4* src = hA16;
    float4* dst = hB16;
    for (int k = 1; k <= K_ITER - 1; ++k) {
        k_pull<0><<<pgrid, NPB * TPN, 0, stream>>>(rowptr, epack, scale,
                                                   (const float4*)x, src, dst);
        float4* t = src; src = dst; dst = t;
    }
    k_pull<1><<<pgrid, NPB * TPN, 0, stream>>>(rowptr, epack, scale,
                                               (const float4*)x, src, d_out);
}